// Round 6
// baseline (2028.300 us; speedup 1.0000x reference)
//
#include <hip/hip_runtime.h>
#include <stdint.h>

#define NB   32
#define NC   256
#define NPTS 4096
#define KCL  8
#define TILE 128
#define KC   384          // OpenBLAS SGEMM_DEFAULT_Q (Haswell/Zen)
#define NPANEL 11         // 10*384 + 256

// Contiguous-axis pairwise, numpy npyv SIMD path on AVX512 (nlanes=16):
// used for ||cent||^2 (cent is C-contiguous). n=256 -> two 128 blocks;
// block: 8 zmm accs (one load each), lanewise tree, horizontal tree 8/4/2/1.
__device__ float np_sumsq_avx512(const float* sh) {
  float half[2];
  #pragma unroll
  for (int h = 0; h < 2; ++h) {
    const float* ap = sh + h * 128;
    float rv[16];
    #pragma unroll
    for (int l = 0; l < 16; ++l) {
      float q[8];
      #pragma unroll
      for (int j = 0; j < 8; ++j) {
        float e = ap[16 * j + l];
        q[j] = __fmul_rn(e, e);
      }
      rv[l] = __fadd_rn(__fadd_rn(__fadd_rn(q[0], q[1]), __fadd_rn(q[2], q[3])),
                        __fadd_rn(__fadd_rn(q[4], q[5]), __fadd_rn(q[6], q[7])));
    }
    float t1[8];
    #pragma unroll
    for (int l = 0; l < 8; ++l) t1[l] = __fadd_rn(rv[l], rv[l + 8]);
    float t2[4];
    #pragma unroll
    for (int l = 0; l < 4; ++l) t2[l] = __fadd_rn(t1[l], t1[l + 2 + 2]);
    float t3[2];
    #pragma unroll
    for (int l = 0; l < 2; ++l) t3[l] = __fadd_rn(t2[l], t2[l + 2]);
    half[h] = __fadd_rn(t3[0], t3[1]);
  }
  return __fadd_rn(half[0], half[1]);
}

// ---------------- init: centroids = first 8 points ----------------
__global__ __launch_bounds__(256) void k_init(const float* __restrict__ X,
                                              float* __restrict__ centT,
                                              float* __restrict__ cnorm) {
  const int b = blockIdx.x >> 3, k = blockIdx.x & 7, c = threadIdx.x;
  __shared__ float sarr[NC];
  float v = X[(size_t)b * NC * NPTS + (size_t)c * NPTS + k];
  centT[(b * NC + c) * KCL + k] = v;
  sarr[c] = v;
  __syncthreads();
  if (c == 0) cnorm[b * KCL + k] = np_sumsq_avx512(sarr);
}

// ---------------- assign: labels via host-numerics-faithful fp32 ----------------
__global__ __launch_bounds__(256) void k_assign(const float* __restrict__ X,
                                                const float* __restrict__ centT,
                                                const float* __restrict__ cnorm,
                                                int* __restrict__ lab) {
  const int blk = blockIdx.x;
  const int b   = blk >> 5;
  const int n0  = (blk & 31) * TILE;
  const int t   = threadIdx.x;
  __shared__ __align__(16) float xs[NC * (TILE + 1)];   // 132 KB

  const float* Xb = X + (size_t)b * NC * NPTS + n0;
  #pragma unroll 4
  for (int it = 0; it < 32; ++it) {
    int flat = it * 256 + t;
    int c = flat >> 5;
    int j4 = (flat & 31) << 2;
    float4 v = *(const float4*)(Xb + (size_t)c * NPTS + j4);
    float* d = &xs[c * (TILE + 1) + j4];
    d[0] = v.x; d[1] = v.y; d[2] = v.z; d[3] = v.w;
  }
  __syncthreads();

  if (t < TILE) {
    // a = sum(x*x, axis=1) on F-contig xx: numpy reorders axes -> the reduce
    // axis is OUTER, computation is out += xx[:,c] -> SEQUENTIAL left fold.
    float a = 0.f;
    for (int c = 0; c < NC; ++c) {
      float x = xs[c * (TILE + 1) + t];
      a = __fadd_rn(a, __fmul_rn(x, x));
    }
    // b_k = sequential fp32 FMA chain over c = 0..255 (BLAS micro-kernel order)
    float bb[8];
    #pragma unroll
    for (int k = 0; k < 8; ++k) bb[k] = 0.f;
    const float4* cw = (const float4*)(centT + (size_t)b * NC * KCL); // uniform -> s_load
    #pragma unroll 4
    for (int c = 0; c < NC; ++c) {
      float x = xs[c * (TILE + 1) + t];
      float4 c0 = cw[c * 2], c1 = cw[c * 2 + 1];
      bb[0] = __builtin_fmaf(x, c0.x, bb[0]);
      bb[1] = __builtin_fmaf(x, c0.y, bb[1]);
      bb[2] = __builtin_fmaf(x, c0.z, bb[2]);
      bb[3] = __builtin_fmaf(x, c0.w, bb[3]);
      bb[4] = __builtin_fmaf(x, c1.x, bb[4]);
      bb[5] = __builtin_fmaf(x, c1.y, bb[5]);
      bb[6] = __builtin_fmaf(x, c1.z, bb[6]);
      bb[7] = __builtin_fmaf(x, c1.w, bb[7]);
    }
    int lb = 0; float best = 3.4e38f;
    #pragma unroll
    for (int k = 0; k < 8; ++k) {
      float d = __fadd_rn(__fsub_rn(a, __fmul_rn(2.0f, bb[k])), cnorm[b * KCL + k]);
      if (d < best) { best = d; lb = k; }
    }
    lab[b * NPTS + n0 + t] = lb;
  }
}

// ---------------- per-panel partial sums (sgemm KC-panel emulation) ----------------
__global__ __launch_bounds__(256) void k_psum(const float* __restrict__ X,
                                              const int* __restrict__ lab,
                                              float* __restrict__ pp,
                                              int* __restrict__ pc) {
  const int blk = blockIdx.x;
  const int b = blk / 88, r = blk % 88, panel = r >> 3, cg = r & 7;
  const int p0 = panel * KC;
  const int t = threadIdx.x, k = t & 7, cl_ = t >> 3;
  __shared__ __align__(16) float xsl[32 * 388];   // 49.7 KB
  __shared__ __align__(16) int   labs[KC];

  const float* Xb = X + (size_t)b * NC * NPTS + (size_t)(cg * 32) * NPTS + p0;
  const int* Lb = lab + b * NPTS + p0;
  if (panel < 10) {   // len = 384
    for (int i = t; i < 96; i += 256) ((int4*)labs)[i] = ((const int4*)Lb)[i];
    for (int i = t; i < 3072; i += 256) {
      int rr = i / 96, qq = i - rr * 96;
      float4 v = *(const float4*)(Xb + (size_t)rr * NPTS + (qq << 2));
      float* d = &xsl[rr * 388 + (qq << 2)];
      d[0] = v.x; d[1] = v.y; d[2] = v.z; d[3] = v.w;
    }
  } else {            // len = 256
    for (int i = t; i < 64; i += 256) ((int4*)labs)[i] = ((const int4*)Lb)[i];
    for (int i = t; i < 2048; i += 256) {
      int rr = i >> 6, qq = i & 63;
      float4 v = *(const float4*)(Xb + (size_t)rr * NPTS + (qq << 2));
      float* d = &xsl[rr * 388 + (qq << 2)];
      d[0] = v.x; d[1] = v.y; d[2] = v.z; d[3] = v.w;
    }
  }
  __syncthreads();

  const int len = (panel < 10) ? KC : (NPTS - 10 * KC);
  float pa = 0.f; int cnt = 0;
  for (int j = 0; j < len; j += 4) {
    int4  l4 = *(const int4*)&labs[j];
    float4 x4 = *(const float4*)&xsl[cl_ * 388 + j];
    if (l4.x == k) { pa = __fadd_rn(pa, x4.x); ++cnt; }
    if (l4.y == k) { pa = __fadd_rn(pa, x4.y); ++cnt; }
    if (l4.z == k) { pa = __fadd_rn(pa, x4.z); ++cnt; }
    if (l4.w == k) { pa = __fadd_rn(pa, x4.w); ++cnt; }
  }
  pp[(size_t)((b * NPANEL + panel) * KCL + k) * NC + cg * 32 + cl_] = pa;
  if (cl_ == 0) pc[(b * NPANEL + panel) * KCL + k] = cnt;
}

// ---------------- ordered panel combine -> centroids + cnorm ----------------
__global__ __launch_bounds__(256) void k_combine(const float* __restrict__ pp,
                                                 const int* __restrict__ pc,
                                                 float* __restrict__ centT,
                                                 float* __restrict__ cnorm) {
  const int b = blockIdx.x >> 3, k = blockIdx.x & 7, c = threadIdx.x;
  float C = 0.f;          // 0 + x is exact: ordered fold == BLAS C-update
  int cnt = 0;
  for (int pnl = 0; pnl < NPANEL; ++pnl) {
    C = __fadd_rn(C, pp[(size_t)((b * NPANEL + pnl) * KCL + k) * NC + c]);
    cnt += pc[(b * NPANEL + pnl) * KCL + k];
  }
  const float mean = __fdiv_rn(C, (float)((cnt > 0) ? cnt : 1));
  const int ci = (b * NC + c) * KCL + k;
  float nv = (cnt > 0) ? mean : centT[ci];
  centT[ci] = nv;
  __shared__ float sarr[NC];
  sarr[c] = nv;
  __syncthreads();
  if (c == 0) cnorm[b * KCL + k] = np_sumsq_avx512(sarr);
}

// ---------------- final output: einsum = pure sequential chain over p ----------------
__global__ __launch_bounds__(256) void k_final(const float* __restrict__ X,
                                               const int* __restrict__ lab,
                                               float* __restrict__ out) {
  const int b = blockIdx.x >> 3, cg = blockIdx.x & 7;
  const int t = threadIdx.x, k = t & 7, cl_ = t >> 3;
  __shared__ __align__(16) float xsl[32 * 388];
  __shared__ __align__(16) int   labs[NPTS];     // 16 KB

  for (int i = t; i < 1024; i += 256)
    ((int4*)labs)[i] = ((const int4*)(lab + b * NPTS))[i];

  const float* Xrow = X + (size_t)b * NC * NPTS + (size_t)(cg * 32) * NPTS;
  float pa = 0.f; int cnt = 0;
  for (int ch = 0; ch < NPANEL; ++ch) {
    const int p0 = ch * KC;
    __syncthreads();
    if (ch < 10) {
      for (int i = t; i < 3072; i += 256) {
        int rr = i / 96, qq = i - rr * 96;
        float4 v = *(const float4*)(Xrow + (size_t)rr * NPTS + p0 + (qq << 2));
        float* d = &xsl[rr * 388 + (qq << 2)];
        d[0] = v.x; d[1] = v.y; d[2] = v.z; d[3] = v.w;
      }
    } else {
      for (int i = t; i < 2048; i += 256) {
        int rr = i >> 6, qq = i & 63;
        float4 v = *(const float4*)(Xrow + (size_t)rr * NPTS + p0 + (qq << 2));
        float* d = &xsl[rr * 388 + (qq << 2)];
        d[0] = v.x; d[1] = v.y; d[2] = v.z; d[3] = v.w;
      }
    }
    __syncthreads();
    const int len = (ch < 10) ? KC : (NPTS - 10 * KC);
    for (int j = 0; j < len; j += 4) {
      int4  l4 = *(const int4*)&labs[p0 + j];
      float4 x4 = *(const float4*)&xsl[cl_ * 388 + j];
      if (l4.x == k) { pa = __fadd_rn(pa, x4.x); ++cnt; }
      if (l4.y == k) { pa = __fadd_rn(pa, x4.y); ++cnt; }
      if (l4.z == k) { pa = __fadd_rn(pa, x4.z); ++cnt; }
      if (l4.w == k) { pa = __fadd_rn(pa, x4.w); ++cnt; }
    }
  }
  out[(b * KCL + k) * NC + cg * 32 + cl_] =
      (cnt > 0) ? __fdiv_rn(pa, (float)cnt) : 0.0f;
}

extern "C" void kernel_launch(void* const* d_in, const int* in_sizes, int n_in,
                              void* d_out, int out_size, void* d_ws, size_t ws_size,
                              hipStream_t stream) {
  const float* X = (const float*)d_in[0];
  float* out = (float*)d_out;

  // ws: centT f[32*256*8] | cnorm f[32*8] | lab i[32*4096] | pp f[32*11*8*256] | pc i[32*11*8]
  float* centT = (float*)d_ws;
  float* cnorm = centT + (size_t)NB * NC * KCL;
  int*   lab   = (int*)(cnorm + NB * KCL);
  float* pp    = (float*)(lab + (size_t)NB * NPTS);
  int*   pc    = (int*)(pp + (size_t)NB * NPANEL * KCL * NC);

  k_init<<<NB * KCL, 256, 0, stream>>>(X, centT, cnorm);
  for (int it = 0; it < 10; ++it) {
    k_assign<<<NB * 32, 256, 0, stream>>>(X, centT, cnorm, lab);
    k_psum<<<NB * NPANEL * KCL, 256, 0, stream>>>(X, lab, pp, pc);
    k_combine<<<NB * KCL, 256, 0, stream>>>(pp, pc, centT, cnorm);
  }
  k_assign<<<NB * 32, 256, 0, stream>>>(X, centT, cnorm, lab);
  k_final<<<NB * KCL, 256, 0, stream>>>(X, lab, out);
}